// Round 1
// baseline (154.601 us; speedup 1.0000x reference)
//
#include <hip/hip_runtime.h>

// DetectionLoss: NB=3 boxes, C=20 classes, S=7 grid, D=35 ch, B=8192
// N_cells = B*S*S = 401408. Pure map-reduce, memory-bound (~112 MB read).

#define NBOX 3
#define NCLS 20
#define SDIM 7
#define DCH  35
#define CPB  128      // cells per block == threads per block
#define NTHREADS 128

__global__ __launch_bounds__(NTHREADS) void detloss_kernel(
    const float* __restrict__ out_g, const float* __restrict__ tgt_g,
    float* __restrict__ result, int n_cells, float inv_nB)
{
    __shared__ float s_out[CPB * DCH];   // 17920 B
    __shared__ float s_tgt[CPB * DCH];   // 17920 B
    __shared__ float s_part[NTHREADS / 64];

    const int tid = threadIdx.x;
    const long long total = (long long)n_cells * DCH;
    const long long base  = (long long)blockIdx.x * (CPB * DCH);
    const int n4 = CPB * DCH / 4;        // 1120 float4 per tensor

    // ---- cooperative float4 staging (coalesced) ----
    if (base + (long long)CPB * DCH <= total) {
        const float4* go = (const float4*)(out_g + base);
        const float4* gt = (const float4*)(tgt_g + base);
        float4* so = (float4*)s_out;
        float4* st = (float4*)s_tgt;
        for (int i = tid; i < n4; i += NTHREADS) {
            so[i] = go[i];
            st[i] = gt[i];
        }
    } else {
        // tail block (not hit for B=8192, but keep correct in general)
        for (int i = tid; i < CPB * DCH; i += NTHREADS) {
            long long gi = base + i;
            s_out[i] = (gi < total) ? out_g[gi] : 0.0f;
            s_tgt[i] = (gi < total) ? tgt_g[gi] : 1.0f; // conf!=0 and !=1 safe? use 0.5
        }
    }
    __syncthreads();

    float loss = 0.0f;
    const int cell = blockIdx.x * CPB + tid;
    if (cell < n_cells) {
        const float* o = s_out + tid * DCH;
        const float* g = s_tgt + tid * DCH;

        // target box (box 0) -> xyxy, exactly as reference
        const float tx  = g[0] / 7.0f, ty = g[1] / 7.0f;
        const float thw = 0.5f * g[2], thh = 0.5f * g[3];
        const float tx1 = tx - thw, ty1 = ty - thh;
        const float tx2 = tx + thw, ty2 = ty + thh;
        const float a2  = (tx2 - tx1) * (ty2 - ty1);

        const float conf_t = g[4];
        const float obj    = (conf_t == 1.0f) ? 1.0f : 0.0f;
        const float noobj  = (conf_t == 0.0f) ? 1.0f : 0.0f;

        int   best = 0;
        float biou = -__builtin_inff();   // strict > => first-index-wins ties (matches argmax)
        float conf_sq = 0.0f;

        #pragma unroll
        for (int i = 0; i < NBOX; ++i) {
            const float px  = o[5*i]   / 7.0f;
            const float py  = o[5*i+1] / 7.0f;
            const float phw = 0.5f * o[5*i+2];
            const float phh = 0.5f * o[5*i+3];
            const float px1 = px - phw, py1 = py - phh;
            const float px2 = px + phw, py2 = py + phh;

            const float ltx = fmaxf(px1, tx1), lty = fmaxf(py1, ty1);
            const float rbx = fminf(px2, tx2), rby = fminf(py2, ty2);
            const float w = fmaxf(rbx - ltx, 0.0f);
            const float h = fmaxf(rby - lty, 0.0f);
            const float inter = w * h;
            const float a1 = (px2 - px1) * (py2 - py1);
            const float iou = inter / (a1 + a2 - inter);
            if (iou > biou) { biou = iou; best = i; }

            const float dc = o[5*i+4] - g[5*i+4];
            conf_sq += dc * dc;
        }

        // noobj conf loss (scale 0.5)
        loss = 0.5f * noobj * conf_sq;

        // responsible-box losses (only count when obj==1)
        const int b5 = 5 * best;
        const float dx = o[b5]   - g[b5];
        const float dy = o[b5+1] - g[b5+1];
        const float xyl = dx*dx + dy*dy;
        const float dw = sqrtf(o[b5+2]) - sqrtf(g[b5+2]);
        const float dh = sqrtf(o[b5+3]) - sqrtf(g[b5+3]);
        const float whl = dw*dw + dh*dh;
        const float dcf = o[b5+4] - biou;
        const float contain = dcf * dcf;

        float cls = 0.0f;
        #pragma unroll
        for (int c = 0; c < NCLS; ++c) {
            const float d = o[5*NBOX + c] - g[5*NBOX + c];
            cls += d * d;
        }

        loss += obj * (5.0f * (xyl + whl) + contain + cls);
        loss *= inv_nB;
    }

    // ---- reduction: wave64 shuffle -> LDS -> one atomic per block ----
    #pragma unroll
    for (int off = 32; off > 0; off >>= 1)
        loss += __shfl_down(loss, off);
    if ((tid & 63) == 0) s_part[tid >> 6] = loss;
    __syncthreads();
    if (tid == 0) {
        float tot = s_part[0];
        #pragma unroll
        for (int w = 1; w < NTHREADS / 64; ++w) tot += s_part[w];
        atomicAdd(result, tot);
    }
}

extern "C" void kernel_launch(void* const* d_in, const int* in_sizes, int n_in,
                              void* d_out, int out_size, void* d_ws, size_t ws_size,
                              hipStream_t stream) {
    const float* out_p = (const float*)d_in[0];
    const float* tgt_p = (const float*)d_in[1];
    float* res = (float*)d_out;

    const int n_cells = in_sizes[0] / DCH;           // B*S*S = 401408
    const int nB = n_cells / (SDIM * SDIM);          // 8192
    const float inv_nB = 1.0f / (float)nB;

    hipMemsetAsync(d_out, 0, (size_t)out_size * sizeof(float), stream);

    const int blocks = (n_cells + CPB - 1) / CPB;    // 3136
    hipLaunchKernelGGL(detloss_kernel, dim3(blocks), dim3(NTHREADS), 0, stream,
                       out_p, tgt_p, res, n_cells, inv_nB);
}

// Round 2
// 135.998 us; speedup vs baseline: 1.1368x; 1.1368x over previous
//
#include <hip/hip_runtime.h>

// DetectionLoss: NB=3 boxes, C=20 classes, S=7 grid, D=35 ch, B=8192
// N_cells = B*S*S = 401408. Pure map-reduce, memory-bound (~112 MB read).
// R2: removed single-address atomicAdd (3136 serialized device-scope atomics
// was the 68us bottleneck: HBM 10%, VALU 6% -> pure serialization). Now
// block partials -> d_ws, second 1-block kernel reduces.

#define NBOX 3
#define NCLS 20
#define SDIM 7
#define DCH  35
#define CPB  128      // cells per block == threads per block
#define NTHREADS 128

__global__ __launch_bounds__(NTHREADS) void detloss_kernel(
    const float* __restrict__ out_g, const float* __restrict__ tgt_g,
    float* __restrict__ partials, int n_cells, float inv_nB)
{
    __shared__ float s_out[CPB * DCH];   // 17920 B
    __shared__ float s_tgt[CPB * DCH];   // 17920 B
    __shared__ float s_part[NTHREADS / 64];

    const int tid = threadIdx.x;
    const long long total = (long long)n_cells * DCH;
    const long long base  = (long long)blockIdx.x * (CPB * DCH);
    const int n4 = CPB * DCH / 4;        // 1120 float4 per tensor

    // ---- cooperative float4 staging (coalesced) ----
    if (base + (long long)CPB * DCH <= total) {
        const float4* go = (const float4*)(out_g + base);
        const float4* gt = (const float4*)(tgt_g + base);
        float4* so = (float4*)s_out;
        float4* st = (float4*)s_tgt;
        for (int i = tid; i < n4; i += NTHREADS) {
            so[i] = go[i];
            st[i] = gt[i];
        }
    } else {
        for (int i = tid; i < CPB * DCH; i += NTHREADS) {
            long long gi = base + i;
            s_out[i] = (gi < total) ? out_g[gi] : 0.0f;
            s_tgt[i] = (gi < total) ? tgt_g[gi] : 0.5f;
        }
    }
    __syncthreads();

    float loss = 0.0f;
    const int cell = blockIdx.x * CPB + tid;
    if (cell < n_cells) {
        const float* o = s_out + tid * DCH;
        const float* g = s_tgt + tid * DCH;

        // target box (box 0) -> xyxy, exactly as reference
        const float tx  = g[0] / 7.0f, ty = g[1] / 7.0f;
        const float thw = 0.5f * g[2], thh = 0.5f * g[3];
        const float tx1 = tx - thw, ty1 = ty - thh;
        const float tx2 = tx + thw, ty2 = ty + thh;
        const float a2  = (tx2 - tx1) * (ty2 - ty1);

        const float conf_t = g[4];
        const float obj    = (conf_t == 1.0f) ? 1.0f : 0.0f;
        const float noobj  = (conf_t == 0.0f) ? 1.0f : 0.0f;

        int   best = 0;
        float biou = -__builtin_inff();   // strict > => first-index-wins ties (matches argmax)
        float conf_sq = 0.0f;

        #pragma unroll
        for (int i = 0; i < NBOX; ++i) {
            const float px  = o[5*i]   / 7.0f;
            const float py  = o[5*i+1] / 7.0f;
            const float phw = 0.5f * o[5*i+2];
            const float phh = 0.5f * o[5*i+3];
            const float px1 = px - phw, py1 = py - phh;
            const float px2 = px + phw, py2 = py + phh;

            const float ltx = fmaxf(px1, tx1), lty = fmaxf(py1, ty1);
            const float rbx = fminf(px2, tx2), rby = fminf(py2, ty2);
            const float w = fmaxf(rbx - ltx, 0.0f);
            const float h = fmaxf(rby - lty, 0.0f);
            const float inter = w * h;
            const float a1 = (px2 - px1) * (py2 - py1);
            const float iou = inter / (a1 + a2 - inter);
            if (iou > biou) { biou = iou; best = i; }

            const float dc = o[5*i+4] - g[5*i+4];
            conf_sq += dc * dc;
        }

        // noobj conf loss (scale 0.5)
        loss = 0.5f * noobj * conf_sq;

        // responsible-box losses (only count when obj==1)
        const int b5 = 5 * best;
        const float dx = o[b5]   - g[b5];
        const float dy = o[b5+1] - g[b5+1];
        const float xyl = dx*dx + dy*dy;
        const float dw = sqrtf(o[b5+2]) - sqrtf(g[b5+2]);
        const float dh = sqrtf(o[b5+3]) - sqrtf(g[b5+3]);
        const float whl = dw*dw + dh*dh;
        const float dcf = o[b5+4] - biou;
        const float contain = dcf * dcf;

        float cls = 0.0f;
        #pragma unroll
        for (int c = 0; c < NCLS; ++c) {
            const float d = o[5*NBOX + c] - g[5*NBOX + c];
            cls += d * d;
        }

        loss += obj * (5.0f * (xyl + whl) + contain + cls);
        loss *= inv_nB;
    }

    // ---- reduction: wave64 shuffle -> LDS -> ONE partial per block ----
    #pragma unroll
    for (int off = 32; off > 0; off >>= 1)
        loss += __shfl_down(loss, off);
    if ((tid & 63) == 0) s_part[tid >> 6] = loss;
    __syncthreads();
    if (tid == 0) {
        float tot = s_part[0];
        #pragma unroll
        for (int w = 1; w < NTHREADS / 64; ++w) tot += s_part[w];
        partials[blockIdx.x] = tot;        // distinct address per block: no contention
    }
}

__global__ __launch_bounds__(1024) void reduce_kernel(
    const float* __restrict__ partials, float* __restrict__ out, int n)
{
    __shared__ float s[1024 / 64];
    float v = 0.0f;
    for (int i = threadIdx.x; i < n; i += 1024) v += partials[i];
    #pragma unroll
    for (int off = 32; off > 0; off >>= 1)
        v += __shfl_down(v, off);
    if ((threadIdx.x & 63) == 0) s[threadIdx.x >> 6] = v;
    __syncthreads();
    if (threadIdx.x == 0) {
        float t = 0.0f;
        #pragma unroll
        for (int w = 0; w < 1024 / 64; ++w) t += s[w];
        out[0] = t;
    }
}

extern "C" void kernel_launch(void* const* d_in, const int* in_sizes, int n_in,
                              void* d_out, int out_size, void* d_ws, size_t ws_size,
                              hipStream_t stream) {
    const float* out_p = (const float*)d_in[0];
    const float* tgt_p = (const float*)d_in[1];
    float* res = (float*)d_out;
    float* part = (float*)d_ws;

    const int n_cells = in_sizes[0] / DCH;           // B*S*S = 401408
    const int nB = n_cells / (SDIM * SDIM);          // 8192
    const float inv_nB = 1.0f / (float)nB;

    const int blocks = (n_cells + CPB - 1) / CPB;    // 3136
    hipLaunchKernelGGL(detloss_kernel, dim3(blocks), dim3(NTHREADS), 0, stream,
                       out_p, tgt_p, part, n_cells, inv_nB);
    hipLaunchKernelGGL(reduce_kernel, dim3(1), dim3(1024), 0, stream,
                       part, res, blocks);
}

// Round 3
// 128.852 us; speedup vs baseline: 1.1998x; 1.0555x over previous
//
#include <hip/hip_runtime.h>

// DetectionLoss: NB=3, C=20, S=7, D=35, B=8192 -> 401408 cells, ~112 MB read.
// R3: staging via __builtin_amdgcn_global_load_lds (16B DMA, fire-and-forget).
// R2's register round-trip loop had fractional trip count (8.75) -> only ~2
// loads in flight/wave -> HBM at 17%. Now 17.5 DMAs/wave issue before one
// vmcnt drain at the barrier. 401408 = 3136*128 exactly: no tail, no OOB.

#define NBOX 3
#define NCLS 20
#define SDIM 7
#define DCH  35
#define CPB  128                  // cells per block == threads per block
#define NTHREADS 128
#define NF4  (CPB * DCH / 4)      // 1120 float4 per tensor per block
#define NF4T (2 * NF4)            // 2240 flat

typedef __attribute__((address_space(3))) unsigned int  lds_u32;
typedef const __attribute__((address_space(1))) unsigned int glob_u32;

__global__ __launch_bounds__(NTHREADS) void detloss_kernel(
    const float* __restrict__ out_g, const float* __restrict__ tgt_g,
    float* __restrict__ partials, int n_cells, float inv_nB)
{
    __shared__ float4 s_buf[NF4T];          // 35840 B: [0,1120)=out, [1120,2240)=tgt
    __shared__ float  s_part[NTHREADS / 64];

    const int tid = threadIdx.x;
    const long long blk_f4 = (long long)blockIdx.x * NF4;
    const float4* go = (const float4*)out_g + blk_f4;
    const float4* gt = (const float4*)tgt_g + blk_f4;

    // ---- async global->LDS DMA, 16B per lane per issue ----
    #pragma unroll
    for (int j = 0; j < 17; ++j) {
        const int k = j * NTHREADS + tid;                 // flat float4 index
        const float4* src = (k < NF4) ? (go + k) : (gt + (k - NF4));
        __builtin_amdgcn_global_load_lds((glob_u32*)src, (lds_u32*)&s_buf[k], 16, 0, 0);
    }
    if (tid < 64) {                                       // half-iteration: wave 0 only
        const int k = 17 * NTHREADS + tid;                // 2176..2239 -> tgt section
        __builtin_amdgcn_global_load_lds((glob_u32*)(gt + (k - NF4)),
                                         (lds_u32*)&s_buf[k], 16, 0, 0);
    }
    __syncthreads();   // compiler emits s_waitcnt vmcnt(0) before s_barrier

    const float* sf = (const float*)s_buf;
    const float* o = sf + tid * DCH;
    const float* g = sf + 4 * NF4 + tid * DCH;

    // target box (box 0) -> xyxy, exactly as reference
    const float tx  = g[0] / 7.0f, ty = g[1] / 7.0f;
    const float thw = 0.5f * g[2], thh = 0.5f * g[3];
    const float tx1 = tx - thw, ty1 = ty - thh;
    const float tx2 = tx + thw, ty2 = ty + thh;
    const float a2  = (tx2 - tx1) * (ty2 - ty1);

    const float conf_t = g[4];
    const float obj    = (conf_t == 1.0f) ? 1.0f : 0.0f;
    const float noobj  = (conf_t == 0.0f) ? 1.0f : 0.0f;

    int   best = 0;
    float biou = -__builtin_inff();   // strict > => first-index-wins (matches argmax)
    float conf_sq = 0.0f;

    #pragma unroll
    for (int i = 0; i < NBOX; ++i) {
        const float px  = o[5*i]   / 7.0f;
        const float py  = o[5*i+1] / 7.0f;
        const float phw = 0.5f * o[5*i+2];
        const float phh = 0.5f * o[5*i+3];
        const float px1 = px - phw, py1 = py - phh;
        const float px2 = px + phw, py2 = py + phh;

        const float ltx = fmaxf(px1, tx1), lty = fmaxf(py1, ty1);
        const float rbx = fminf(px2, tx2), rby = fminf(py2, ty2);
        const float w = fmaxf(rbx - ltx, 0.0f);
        const float h = fmaxf(rby - lty, 0.0f);
        const float inter = w * h;
        const float a1 = (px2 - px1) * (py2 - py1);
        const float iou = inter / (a1 + a2 - inter);
        if (iou > biou) { biou = iou; best = i; }

        const float dc = o[5*i+4] - g[5*i+4];
        conf_sq += dc * dc;
    }

    float loss = 0.5f * noobj * conf_sq;

    const int b5 = 5 * best;
    const float dx = o[b5]   - g[b5];
    const float dy = o[b5+1] - g[b5+1];
    const float xyl = dx*dx + dy*dy;
    const float dw = sqrtf(o[b5+2]) - sqrtf(g[b5+2]);
    const float dh = sqrtf(o[b5+3]) - sqrtf(g[b5+3]);
    const float whl = dw*dw + dh*dh;
    const float dcf = o[b5+4] - biou;
    const float contain = dcf * dcf;

    float cls = 0.0f;
    #pragma unroll
    for (int c = 0; c < NCLS; ++c) {
        const float d = o[5*NBOX + c] - g[5*NBOX + c];
        cls += d * d;
    }

    loss += obj * (5.0f * (xyl + whl) + contain + cls);
    loss *= inv_nB;

    // ---- wave64 shuffle -> LDS -> one partial per block ----
    #pragma unroll
    for (int off = 32; off > 0; off >>= 1)
        loss += __shfl_down(loss, off);
    if ((tid & 63) == 0) s_part[tid >> 6] = loss;
    __syncthreads();
    if (tid == 0) {
        float tot = s_part[0];
        #pragma unroll
        for (int w = 1; w < NTHREADS / 64; ++w) tot += s_part[w];
        partials[blockIdx.x] = tot;
    }
}

__global__ __launch_bounds__(1024) void reduce_kernel(
    const float* __restrict__ partials, float* __restrict__ out, int n)
{
    __shared__ float s[1024 / 64];
    float v = 0.0f;
    for (int i = threadIdx.x; i < n; i += 1024) v += partials[i];
    #pragma unroll
    for (int off = 32; off > 0; off >>= 1)
        v += __shfl_down(v, off);
    if ((threadIdx.x & 63) == 0) s[threadIdx.x >> 6] = v;
    __syncthreads();
    if (threadIdx.x == 0) {
        float t = 0.0f;
        #pragma unroll
        for (int w = 0; w < 1024 / 64; ++w) t += s[w];
        out[0] = t;
    }
}

extern "C" void kernel_launch(void* const* d_in, const int* in_sizes, int n_in,
                              void* d_out, int out_size, void* d_ws, size_t ws_size,
                              hipStream_t stream) {
    const float* out_p = (const float*)d_in[0];
    const float* tgt_p = (const float*)d_in[1];
    float* res  = (float*)d_out;
    float* part = (float*)d_ws;

    const int n_cells = in_sizes[0] / DCH;           // 401408
    const int nB = n_cells / (SDIM * SDIM);          // 8192
    const float inv_nB = 1.0f / (float)nB;

    const int blocks = n_cells / CPB;                // 3136 (exact)
    hipLaunchKernelGGL(detloss_kernel, dim3(blocks), dim3(NTHREADS), 0, stream,
                       out_p, tgt_p, part, n_cells, inv_nB);
    hipLaunchKernelGGL(reduce_kernel, dim3(1), dim3(1024), 0, stream,
                       part, res, blocks);
}